// Round 3
// baseline (8554.687 us; speedup 1.0000x reference)
//
#include <hip/hip_runtime.h>
#include <hip/hip_bf16.h>
#include <stdint.h>

// 2-layer LSTM, B=32 T=1024 D=256 H=512, fc -> 256.
// R11 = R10's self-tagged-data sync, re-implemented safely:
//  - gathers use __hip_atomic_load (u64, relaxed, AGENT) -- the builtin's
//    cache-bypass semantics are proven by R9's working flag poll; no inline
//    asm in the LSTM kernel at all (R10 likely hung on stale-L1 re-polls or
//    failed RA on the big "+v" asm blocks).
//  - each u32 word = bf16(h)<<16 | (bf16(h) ^ step_tag): per-word checksum.
//    Consumer's gather IS the poll (retry stale quads only). Values are
//    bit-identical to R9's bf16 path; memset-0 / stale-epoch words always
//    fail the tag. No producer drain, no flags, 2 barriers/step.
//  - h0 history: slot s tag = s+1 (slots unique, never overwritten).
//    h1 ring: write-step t tag = t+7 (ring period 4, tags distinct mod lag).
//    Overwrite safety is inductive: verified gather of h1[t-1] implies all
//    peers finished step t-1, hence their reads of slot t&3 (step t-3) done.

typedef __attribute__((ext_vector_type(8))) short bf16x8;
typedef __attribute__((ext_vector_type(4))) float f32x4;
typedef unsigned short u16;

#define TSEQ 1024

static __device__ __forceinline__ float fsig(float x){ return 1.0f/(1.0f+__expf(-x)); }
static __device__ __forceinline__ float ftanh_(float x){ return 2.0f/(1.0f+__expf(-2.0f*x)) - 1.0f; }
static __device__ __forceinline__ u16 f2bf(float v){
  __hip_bfloat16 b = __float2bfloat16(v);
  return *reinterpret_cast<u16*>(&b);
}
static __device__ __forceinline__ float bf2f(u16 u){
  __hip_bfloat16 b; *reinterpret_cast<u16*>(&b) = u;
  return __bfloat162float(b);
}

// async global->LDS, 16B per lane (GEMM staging)
#define GLD_LDS16(g, l) \
  __builtin_amdgcn_global_load_lds((const __attribute__((address_space(1))) uint32_t*)(g), \
                                   (__attribute__((address_space(3))) uint32_t*)(l), 16, 0, 0)

// ---------------------------------------------------------------- utilities
__global__ void split_f32(const float* __restrict__ src, u16* __restrict__ hi,
                          u16* __restrict__ lo, const int n)
{
  for (int i = blockIdx.x*blockDim.x + threadIdx.x; i < n; i += gridDim.x*blockDim.x){
    const float v = src[i];
    const u16 h = f2bf(v);
    hi[i] = h;
    lo[i] = f2bf(v - bf2f(h));
  }
}

__global__ void vec_add(const float* __restrict__ a, const float* __restrict__ b,
                        float* __restrict__ c, const int n)
{
  const int i = blockIdx.x*blockDim.x + threadIdx.x;
  if (i < n) c[i] = a[i] + b[i];
}

// seed h0 slot 0 (h=0, tag 0+1=1) and ring slot 3 (h=0, tag -1+7=6).
// Buffers are memset to 0 beforehand, so unwritten words always fail tags.
__global__ void init_state(uint32_t* h0hisT, uint32_t* ringT)
{
  const int i = blockIdx.x*256 + threadIdx.x;       // 16384 = 64*256
  h0hisT[i] = 1u;                                   // bf16 0, check 0^1
  ringT[3*16384 + i] = 6u;                          // bf16 0, check 0^6
}

// ------------------------------------------------------ split-bf16 MFMA GEMM
// xproj0: C[m][n] = sum_k A[m][k]*W[n][k] + bias[n], M=32768 N=2048 K=256
// 3-term split-bf16: Ah*Wh + Ah*Wl + Al*Wh. Output fp16. (R5-proven, verbatim)
__global__ __launch_bounds__(256, 2) void gemm_split(
    const u16* __restrict__ Ahi, const u16* __restrict__ Alo,
    const u16* __restrict__ Whi, const u16* __restrict__ Wlo,
    const float* __restrict__ bias, _Float16* __restrict__ C,
    const int K)
{
  __shared__ char smem[32768];
  const int tid = threadIdx.x, lane = tid & 63, wid = tid >> 6;
  const int bn = blockIdx.x, bm = blockIdx.y;

  const u16* gptr[8];
  #pragma unroll
  for (int i = 0; i < 8; ++i){
    const int s = i*256 + tid;
    const int mat = s >> 9, tile = (s >> 6) & 7, rr = s & 15, quad = (s >> 4) & 3;
    if (mat == 0 || mat == 3){
      const long row = (long)bm*128 + tile*16 + rr;
      gptr[i] = ((mat == 0) ? Ahi : Alo) + row*(long)K + quad*8;
    } else {
      const long row = (long)bn*128 + tile*16 + rr;
      gptr[i] = ((mat == 1) ? Whi : Wlo) + row*(long)K + quad*8;
    }
  }

  f32x4 acc[4][4];
  #pragma unroll
  for (int a = 0; a < 4; ++a)
    #pragma unroll
    for (int b = 0; b < 4; ++b) acc[a][b] = (f32x4){0.f,0.f,0.f,0.f};

  const int mh = wid & 1, nh = wid >> 1;

  for (int kk = 0; kk < K; kk += 32){
    __syncthreads();
    #pragma unroll
    for (int i = 0; i < 8; ++i)
      GLD_LDS16(gptr[i] + kk, &smem[i*4096 + wid*1024]);
    __syncthreads();
    bf16x8 ah[4], wh_[4], wl_[4], al[4];
    #pragma unroll
    for (int xi = 0; xi < 4; ++xi){
      const int at = mh*4 + xi, wt = nh*4 + xi;
      ah[xi]  = *(const bf16x8*)(&smem[(at*64 + lane)*16]);
      wh_[xi] = *(const bf16x8*)(&smem[8192  + (wt*64 + lane)*16]);
      wl_[xi] = *(const bf16x8*)(&smem[16384 + (wt*64 + lane)*16]);
      al[xi]  = *(const bf16x8*)(&smem[24576 + (at*64 + lane)*16]);
    }
    #pragma unroll
    for (int mi = 0; mi < 4; ++mi)
      #pragma unroll
      for (int ni = 0; ni < 4; ++ni){
        acc[mi][ni] = __builtin_amdgcn_mfma_f32_16x16x32_bf16(ah[mi], wh_[ni], acc[mi][ni], 0,0,0);
        acc[mi][ni] = __builtin_amdgcn_mfma_f32_16x16x32_bf16(ah[mi], wl_[ni], acc[mi][ni], 0,0,0);
        acc[mi][ni] = __builtin_amdgcn_mfma_f32_16x16x32_bf16(al[mi], wh_[ni], acc[mi][ni], 0,0,0);
      }
  }

  const long mbase = (long)bm*128 + mh*64 + (lane >> 4)*4;
  const int  nb    = bn*128 + nh*64 + (lane & 15);
  #pragma unroll
  for (int ni = 0; ni < 4; ++ni){
    const float bv = bias[nb + ni*16];
    #pragma unroll
    for (int mi = 0; mi < 4; ++mi)
      #pragma unroll
      for (int r = 0; r < 4; ++r)
        C[(mbase + mi*16 + r)*2048 + nb + ni*16] = (_Float16)(acc[mi][ni][r] + bv);
  }
}

// -------------------------------------------- fused persistent 2-layer LSTM
// 64 blocks x 512 threads (8 waves). Blocks 0-31: layer 0 (j=blockIdx);
// blocks 32-63: layer 1 (j=blockIdx-32). Wave w: gate g=w>>1, K-half kh=w&1.
// h state: one u32 per element, [slot][j][b][16]:
//   word = bf16(h)<<16 | ((bf16(h) ^ tag) & 0xffff)
__global__ __launch_bounds__(512, 1) void lstm_fused(
    const _Float16* __restrict__ xp,             // [(b,t)][(g,o)]
    const u16* __restrict__ Wh0hi, const u16* __restrict__ Wh0lo,
    const u16* __restrict__ Wh1hi, const u16* __restrict__ Wh1lo,
    const u16* __restrict__ Wx1hi, const u16* __restrict__ Wx1lo,
    const float* __restrict__ bs1,
    uint32_t* __restrict__ h0hisT,               // [1025][16384] u32
    uint32_t* __restrict__ ringT,                // [4][16384] u32
    float* __restrict__ hfin)                    // [32][512] fp32
{
  __shared__ char asmem0[32768];                 // 32 rows x 1KB (r = cg*2+mt)
  __shared__ char asmem1[32768];
  __shared__ float gsmem[8][32][16];
  const int tid = threadIdx.x;
  const int lane = tid & 63;
  const int wid = tid >> 6;                      // wave 0..7
  const int g   = wid >> 1;                      // gate (0=G,1=I,2=F,3=O)
  const int kh  = wid & 1;                       // K half
  const int role = blockIdx.x >> 5;
  const int j = blockIdx.x & 31;                 // o-slice

  // gather source offsets (u64 units within a 16384-word slot):
  // LDS row r=wid*4+i -> (cg=r>>1, mt=r&1); lane l: b=mt*16+(l&15), lq=l>>4;
  // 8 consecutive k = cg*32+lq*8.. -> elem = (cg*2+(lq>>1))*512 + b*16 +
  // (lq&1)*8 + e, e=0..7 -> 4 u64 loads at (elem0>>1)+0..3.
  int f64off[4];
  #pragma unroll
  for (int i = 0; i < 4; ++i){
    const int r = wid*4 + i, cg = r >> 1, mt = r & 1;
    const int bb = mt*16 + (lane & 15);
    const int lq = lane >> 4;
    const int elem0 = (cg*2 + (lq >> 1))*512 + bb*16 + (lq & 1)*8;
    f64off[i] = elem0 >> 1;
  }
  char* const ldst0 = &asmem0[(wid*4)*1024 + lane*16];
  char* const ldst1 = &asmem1[(wid*4)*1024 + lane*16];

  const int b  = tid >> 4, oi = tid & 15;        // per-thread (b, o) cell
  const int og = j*16 + oi;
  const int hoffT = j*512 + b*16 + oi;           // u32 store slot
  float cst = 0.f;

  if (role == 0){
    // ---- layer 0: gates = xp[t] + Wh0 * h0[t-1] ----
    bf16x8 wfh[8], wfl[8];
    {
      const long nrow = g*512 + j*16 + (lane & 15);
      const int kq = (lane >> 4) * 8;
      #pragma unroll
      for (int c = 0; c < 8; ++c){
        const int cg = kh*8 + c;
        wfh[c] = *(const bf16x8*)(Wh0hi + nrow*512 + cg*32 + kq);
        wfl[c] = *(const bf16x8*)(Wh0lo + nrow*512 + cg*32 + kq);
      }
    }
    const long xq = ((long)b << 10)*2048 + j*16 + oi;

    for (int t = 0; t < TSEQ; ++t){
      float xv[4];
      {
        const long base = xq + (long)t*2048;
        #pragma unroll
        for (int gg = 0; gg < 4; ++gg)
          xv[gg] = (float)__builtin_nontemporal_load(xp + base + gg*512);
      }
      { // gather h0[t-1] (slot t, tag t+1): verified u64 loads -> asmem0
        const uint64_t* s = (const uint64_t*)(h0hisT + (size_t)t*16384);
        const uint32_t mag = (uint32_t)t + 1u;
        uint64_t v[16];
        unsigned pend = 0xffffu;
        do {
          #pragma unroll
          for (int i = 0; i < 4; ++i)
            #pragma unroll
            for (int e = 0; e < 4; ++e)
              if (pend & (1u << (i*4+e)))
                v[i*4+e] = __hip_atomic_load(s + f64off[i] + e, __ATOMIC_RELAXED,
                                             __HIP_MEMORY_SCOPE_AGENT);
          #pragma unroll
          for (int q = 0; q < 16; ++q)
            if (pend & (1u << q)){
              const uint32_t w0 = (uint32_t)v[q], w1 = (uint32_t)(v[q] >> 32);
              const uint32_t d = (((w0 >> 16) ^ w0) ^ mag) | (((w1 >> 16) ^ w1) ^ mag);
              if ((d & 0xffffu) == 0) pend &= ~(1u << q);
            }
        } while (__builtin_expect(pend != 0, 0));
        #pragma unroll
        for (int i = 0; i < 4; ++i){
          bf16x8 o;
          #pragma unroll
          for (int e = 0; e < 4; ++e){
            o[2*e]   = (short)(u16)(((uint32_t)v[i*4+e]) >> 16);
            o[2*e+1] = (short)(u16)((uint32_t)(v[i*4+e] >> 48));
          }
          *(bf16x8*)(ldst0 + i*1024) = o;
        }
      }
      __syncthreads();

      f32x4 acc0 = {0.f,0.f,0.f,0.f}, acc1 = {0.f,0.f,0.f,0.f};
      #pragma unroll
      for (int c = 0; c < 8; ++c){
        const int cg = kh*8 + c;
        bf16x8 a0 = *(const bf16x8*)(&asmem0[((cg*2 + 0)*64 + lane)*16]);
        bf16x8 a1 = *(const bf16x8*)(&asmem0[((cg*2 + 1)*64 + lane)*16]);
        acc0 = __builtin_amdgcn_mfma_f32_16x16x32_bf16(a0, wfh[c], acc0, 0,0,0);
        acc1 = __builtin_amdgcn_mfma_f32_16x16x32_bf16(a1, wfh[c], acc1, 0,0,0);
        acc0 = __builtin_amdgcn_mfma_f32_16x16x32_bf16(a0, wfl[c], acc0, 0,0,0);
        acc1 = __builtin_amdgcn_mfma_f32_16x16x32_bf16(a1, wfl[c], acc1, 0,0,0);
      }
      {
        const int bq = (lane >> 4) * 4, ci = lane & 15;
        #pragma unroll
        for (int r = 0; r < 4; ++r){
          gsmem[wid][bq + r][ci]      = acc0[r];
          gsmem[wid][16 + bq + r][ci] = acc1[r];
        }
      }
      __syncthreads();
      {
        const float gv = ftanh_(gsmem[0][b][oi] + gsmem[1][b][oi] + xv[0]);
        const float iv = fsig (gsmem[2][b][oi] + gsmem[3][b][oi] + xv[1]);
        const float fv = fsig (gsmem[4][b][oi] + gsmem[5][b][oi] + xv[2]);
        const float ov = fsig (gsmem[6][b][oi] + gsmem[7][b][oi] + xv[3]);
        cst = fv*cst + iv*gv;
        const float hv = ov * ftanh_(cst);
        const u16 hh = f2bf(hv);
        const uint32_t wrd = ((uint32_t)hh << 16) |
                             ((hh ^ ((uint32_t)t + 2u)) & 0xffffu);
        __hip_atomic_store(h0hisT + (size_t)(t+1)*16384 + hoffT, wrd,
                           __ATOMIC_RELAXED, __HIP_MEMORY_SCOPE_AGENT);
      }
      // no drain, no flag, no trailing barrier: the gsmem barrier above
      // already orders this step's LDS reads before next step's writes.
    }
  } else {
    // ---- layer 1: gates = bs1 + Wx1*h0[t] + Wh1*h1[t-1] ----
    bf16x8 wfh[8], wfl[8], wxh[8], wxl[8];
    {
      const long nrow = g*512 + j*16 + (lane & 15);
      const int kq = (lane >> 4) * 8;
      #pragma unroll
      for (int c = 0; c < 8; ++c){
        const int cg = kh*8 + c;
        wfh[c] = *(const bf16x8*)(Wh1hi + nrow*512 + cg*32 + kq);
        wfl[c] = *(const bf16x8*)(Wh1lo + nrow*512 + cg*32 + kq);
        wxh[c] = *(const bf16x8*)(Wx1hi + nrow*512 + cg*32 + kq);
        wxl[c] = *(const bf16x8*)(Wx1lo + nrow*512 + cg*32 + kq);
      }
    }
    float bv[4];
    #pragma unroll
    for (int gg = 0; gg < 4; ++gg) bv[gg] = bs1[gg*512 + og];

    for (int t = 0; t < TSEQ; ++t){
      { // h0[t] (slot t+1, tag t+2) -> asmem0 ;
        // h1[t-1] (ring slot (t+3)&3, tag t+6) -> asmem1
        const uint64_t* s0 = (const uint64_t*)(h0hisT + (size_t)(t+1)*16384);
        const uint64_t* s1 = (const uint64_t*)(ringT + (size_t)((t+3)&3)*16384);
        const uint32_t mag0 = (uint32_t)t + 2u;
        const uint32_t mag1 = (uint32_t)t + 6u;
        uint64_t v0[16], v1[16];
        unsigned p0 = 0xffffu, p1 = 0xffffu;
        do {
          #pragma unroll
          for (int i = 0; i < 4; ++i)
            #pragma unroll
            for (int e = 0; e < 4; ++e){
              const int q = i*4+e;
              if (p0 & (1u << q))
                v0[q] = __hip_atomic_load(s0 + f64off[i] + e, __ATOMIC_RELAXED,
                                          __HIP_MEMORY_SCOPE_AGENT);
              if (p1 & (1u << q))
                v1[q] = __hip_atomic_load(s1 + f64off[i] + e, __ATOMIC_RELAXED,
                                          __HIP_MEMORY_SCOPE_AGENT);
            }
          #pragma unroll
          for (int q = 0; q < 16; ++q){
            if (p0 & (1u << q)){
              const uint32_t w0 = (uint32_t)v0[q], w1 = (uint32_t)(v0[q] >> 32);
              const uint32_t d = (((w0 >> 16) ^ w0) ^ mag0) | (((w1 >> 16) ^ w1) ^ mag0);
              if ((d & 0xffffu) == 0) p0 &= ~(1u << q);
            }
            if (p1 & (1u << q)){
              const uint32_t w0 = (uint32_t)v1[q], w1 = (uint32_t)(v1[q] >> 32);
              const uint32_t d = (((w0 >> 16) ^ w0) ^ mag1) | (((w1 >> 16) ^ w1) ^ mag1);
              if ((d & 0xffffu) == 0) p1 &= ~(1u << q);
            }
          }
        } while (__builtin_expect((p0 | p1) != 0, 0));
        #pragma unroll
        for (int i = 0; i < 4; ++i){
          bf16x8 o, o2;
          #pragma unroll
          for (int e = 0; e < 4; ++e){
            o[2*e]    = (short)(u16)(((uint32_t)v0[i*4+e]) >> 16);
            o[2*e+1]  = (short)(u16)((uint32_t)(v0[i*4+e] >> 48));
            o2[2*e]   = (short)(u16)(((uint32_t)v1[i*4+e]) >> 16);
            o2[2*e+1] = (short)(u16)((uint32_t)(v1[i*4+e] >> 48));
          }
          *(bf16x8*)(ldst0 + i*1024) = o;
          *(bf16x8*)(ldst1 + i*1024) = o2;
        }
      }
      __syncthreads();

      f32x4 acc0 = {0.f,0.f,0.f,0.f}, acc1 = {0.f,0.f,0.f,0.f};
      #pragma unroll
      for (int c = 0; c < 8; ++c){
        const int cg = kh*8 + c;
        bf16x8 h1a0 = *(const bf16x8*)(&asmem1[((cg*2 + 0)*64 + lane)*16]);
        bf16x8 h1a1 = *(const bf16x8*)(&asmem1[((cg*2 + 1)*64 + lane)*16]);
        acc0 = __builtin_amdgcn_mfma_f32_16x16x32_bf16(h1a0, wfh[c], acc0, 0,0,0);
        acc1 = __builtin_amdgcn_mfma_f32_16x16x32_bf16(h1a1, wfh[c], acc1, 0,0,0);
        acc0 = __builtin_amdgcn_mfma_f32_16x16x32_bf16(h1a0, wfl[c], acc0, 0,0,0);
        acc1 = __builtin_amdgcn_mfma_f32_16x16x32_bf16(h1a1, wfl[c], acc1, 0,0,0);
        bf16x8 h0a0 = *(const bf16x8*)(&asmem0[((cg*2 + 0)*64 + lane)*16]);
        bf16x8 h0a1 = *(const bf16x8*)(&asmem0[((cg*2 + 1)*64 + lane)*16]);
        acc0 = __builtin_amdgcn_mfma_f32_16x16x32_bf16(h0a0, wxh[c], acc0, 0,0,0);
        acc1 = __builtin_amdgcn_mfma_f32_16x16x32_bf16(h0a1, wxh[c], acc1, 0,0,0);
        acc0 = __builtin_amdgcn_mfma_f32_16x16x32_bf16(h0a0, wxl[c], acc0, 0,0,0);
        acc1 = __builtin_amdgcn_mfma_f32_16x16x32_bf16(h0a1, wxl[c], acc1, 0,0,0);
      }
      {
        const int bq = (lane >> 4) * 4, ci = lane & 15;
        #pragma unroll
        for (int r = 0; r < 4; ++r){
          gsmem[wid][bq + r][ci]      = acc0[r];
          gsmem[wid][16 + bq + r][ci] = acc1[r];
        }
      }
      __syncthreads();
      {
        const float gv = ftanh_(gsmem[0][b][oi] + gsmem[1][b][oi] + bv[0]);
        const float iv = fsig (gsmem[2][b][oi] + gsmem[3][b][oi] + bv[1]);
        const float fv = fsig (gsmem[4][b][oi] + gsmem[5][b][oi] + bv[2]);
        const float ov = fsig (gsmem[6][b][oi] + gsmem[7][b][oi] + bv[3]);
        cst = fv*cst + iv*gv;
        const float hv = ov * ftanh_(cst);
        if (t == TSEQ-1) hfin[b*512 + og] = hv;
        const u16 hh = f2bf(hv);
        const uint32_t wrd = ((uint32_t)hh << 16) |
                             ((hh ^ ((uint32_t)t + 7u)) & 0xffffu);
        __hip_atomic_store(ringT + (size_t)(t&3)*16384 + hoffT, wrd,
                           __ATOMIC_RELAXED, __HIP_MEMORY_SCOPE_AGENT);
      }
    }
  }
}

// ------------------------------------------------------------------- FC out
__global__ void fc_kernel(const float* __restrict__ hfin,
                          const float* __restrict__ fcW, const float* __restrict__ fcb,
                          float* __restrict__ out)
{
  __shared__ float hbufs[512];
  const int b = blockIdx.x, tid = threadIdx.x;
  for (int i = tid; i < 512; i += 256)
    hbufs[i] = hfin[b*512 + i];
  __syncthreads();
  float acc = fcb[tid];
  const float4* w4 = (const float4*)(fcW + tid*512);
  #pragma unroll 8
  for (int k = 0; k < 128; ++k){
    const float4 w = w4[k];
    acc += hbufs[4*k]*w.x + hbufs[4*k+1]*w.y + hbufs[4*k+2]*w.z + hbufs[4*k+3]*w.w;
  }
  out[b*256 + tid] = acc;
}

// ---------------------------------------------------------------- launcher
extern "C" void kernel_launch(void* const* d_in, const int* in_sizes, int n_in,
                              void* d_out, int out_size, void* d_ws, size_t ws_size,
                              hipStream_t stream)
{
  const float* x   = (const float*)d_in[0];
  const float* Wx0 = (const float*)d_in[1];
  const float* bx0 = (const float*)d_in[2];
  const float* Wh0 = (const float*)d_in[3];
  const float* bh0 = (const float*)d_in[4];
  const float* Wx1 = (const float*)d_in[5];
  const float* bx1 = (const float*)d_in[6];
  const float* Wh1 = (const float*)d_in[7];
  const float* bh1 = (const float*)d_in[8];
  const float* fcW = (const float*)d_in[9];
  const float* fcb = (const float*)d_in[10];

  char* ws = (char*)d_ws;
  size_t off = 0;
  auto take = [&](size_t sz){ void* p = ws + off; off += sz; return p; };
  _Float16* xp     = (_Float16*)take((size_t)32768*2048*2);    // 128 MiB
  uint32_t* h0hisT = (uint32_t*)take((size_t)1025*16384*4);    // 67.2 MB h0 history
  u16*   xh      = (u16*)take((size_t)8388608*2);
  u16*   xl      = (u16*)take((size_t)8388608*2);
  u16*   wx0h    = (u16*)take((size_t)524288*2);
  u16*   wx0l    = (u16*)take((size_t)524288*2);
  u16*   wh0h    = (u16*)take((size_t)1048576*2);
  u16*   wh0l    = (u16*)take((size_t)1048576*2);
  u16*   wx1h    = (u16*)take((size_t)1048576*2);
  u16*   wx1l    = (u16*)take((size_t)1048576*2);
  u16*   wh1h    = (u16*)take((size_t)1048576*2);
  u16*   wh1l    = (u16*)take((size_t)1048576*2);
  uint32_t* ringT = (uint32_t*)take((size_t)4*16384*4);        // 256 KB h1 ring
  float* hfin    = (float*)take((size_t)32*512*4);
  float* bs0     = (float*)take(2048*4);
  float* bs1     = (float*)take(2048*4);
  (void)in_sizes; (void)n_in; (void)out_size; (void)ws_size;

  // tag hygiene: unwritten words must fail tag checks every launch/replay
  (void)hipMemsetAsync(h0hisT, 0, (size_t)1025*16384*4, stream);
  (void)hipMemsetAsync(ringT,  0, (size_t)4*16384*4, stream);

  split_f32<<<4096,256,0,stream>>>(x,   xh,   xl,   8388608);
  split_f32<<<1024,256,0,stream>>>(Wx0, wx0h, wx0l, 524288);
  split_f32<<<2048,256,0,stream>>>(Wh0, wh0h, wh0l, 1048576);
  split_f32<<<2048,256,0,stream>>>(Wx1, wx1h, wx1l, 1048576);
  split_f32<<<2048,256,0,stream>>>(Wh1, wh1h, wh1l, 1048576);
  vec_add<<<8,256,0,stream>>>(bx0, bh0, bs0, 2048);
  vec_add<<<8,256,0,stream>>>(bx1, bh1, bs1, 2048);
  init_state<<<64,256,0,stream>>>(h0hisT, ringT);

  dim3 gg(16, 256);
  gemm_split<<<gg,256,0,stream>>>(xh, xl, wx0h, wx0l, bs0, xp, 256);
  lstm_fused<<<64,512,0,stream>>>(xp, wh0h, wh0l, wh1h, wh1l, wx1h, wx1l, bs1,
                                  h0hisT, ringT, hfin);
  fc_kernel<<<32,256,0,stream>>>(hfin, fcW, fcb, (float*)d_out);
}

// Round 4
// 7292.318 us; speedup vs baseline: 1.1731x; 1.1731x over previous
//
#include <hip/hip_runtime.h>
#include <hip/hip_bf16.h>
#include <stdint.h>

// 2-layer LSTM, B=32 T=1024 D=256 H=512, fc -> 256.
// R12 = R9's proven flag-poll sync structure (cheap 64-lane poll, stable
// 4.16ms) + tagged h-words (R11's bf16<<16 | bf16^tag format, bit-identical
// values) so the producer-side vmcnt(0) drain can be removed:
//  - producer: data stores -> raw s_barrier (NOT __syncthreads: hipcc lowers
//    that with an implicit vmcnt(0) drain) -> flag store. Flag is a HINT.
//  - consumer: R9 flag poll (64 lanes, 1 line/peer) -> wide gather via
//    __hip_atomic_load u64 (emits sc0|sc1: L1-bypassing, retry-safe; R10's
//    sc1-only asm livelocked on stale L1) -> per-word tag verify -> rare
//    s_sleep(1) backoff resweep (flag-gated, so normally 1 sweep).
// Saves ~1 MALL round trip (~0.8-1.0us) per step off R9's critical path.

typedef __attribute__((ext_vector_type(8))) short bf16x8;
typedef __attribute__((ext_vector_type(4))) float f32x4;
typedef unsigned short u16;

#define TSEQ 1024
#define FSTR 16   // flag stride in u32 units (64B)

static __device__ __forceinline__ float fsig(float x){ return 1.0f/(1.0f+__expf(-x)); }
static __device__ __forceinline__ float ftanh_(float x){ return 2.0f/(1.0f+__expf(-2.0f*x)) - 1.0f; }
static __device__ __forceinline__ u16 f2bf(float v){
  __hip_bfloat16 b = __float2bfloat16(v);
  return *reinterpret_cast<u16*>(&b);
}
static __device__ __forceinline__ float bf2f(u16 u){
  __hip_bfloat16 b; *reinterpret_cast<u16*>(&b) = u;
  return __bfloat162float(b);
}

// async global->LDS, 16B per lane (GEMM staging)
#define GLD_LDS16(g, l) \
  __builtin_amdgcn_global_load_lds((const __attribute__((address_space(1))) uint32_t*)(g), \
                                   (__attribute__((address_space(3))) uint32_t*)(l), 16, 0, 0)

// ---------------------------------------------------------------- utilities
__global__ void split_f32(const float* __restrict__ src, u16* __restrict__ hi,
                          u16* __restrict__ lo, const int n)
{
  for (int i = blockIdx.x*blockDim.x + threadIdx.x; i < n; i += gridDim.x*blockDim.x){
    const float v = src[i];
    const u16 h = f2bf(v);
    hi[i] = h;
    lo[i] = f2bf(v - bf2f(h));
  }
}

__global__ void vec_add(const float* __restrict__ a, const float* __restrict__ b,
                        float* __restrict__ c, const int n)
{
  const int i = blockIdx.x*blockDim.x + threadIdx.x;
  if (i < n) c[i] = a[i] + b[i];
}

// seed h0 slot 0 (h=0, tag 1), ring slot 3 (h=0, tag 6), ready1 slot 0.
// Buffers are memset to 0 beforehand, so unwritten words always fail tags.
__global__ void init_state(uint32_t* h0hisT, uint32_t* ringT, uint32_t* ready1)
{
  const int i = blockIdx.x*256 + threadIdx.x;       // 16384 = 64*256
  h0hisT[i] = 1u;                                   // bf16 0, check 0^1
  ringT[3*16384 + i] = 6u;                          // bf16 0, check 0^6
  if (i < 32) ready1[i*FSTR] = 1;
}

// ------------------------------------------------------ split-bf16 MFMA GEMM
// xproj0: C[m][n] = sum_k A[m][k]*W[n][k] + bias[n], M=32768 N=2048 K=256
// 3-term split-bf16: Ah*Wh + Ah*Wl + Al*Wh. Output fp16. (R5-proven, verbatim)
__global__ __launch_bounds__(256, 2) void gemm_split(
    const u16* __restrict__ Ahi, const u16* __restrict__ Alo,
    const u16* __restrict__ Whi, const u16* __restrict__ Wlo,
    const float* __restrict__ bias, _Float16* __restrict__ C,
    const int K)
{
  __shared__ char smem[32768];
  const int tid = threadIdx.x, lane = tid & 63, wid = tid >> 6;
  const int bn = blockIdx.x, bm = blockIdx.y;

  const u16* gptr[8];
  #pragma unroll
  for (int i = 0; i < 8; ++i){
    const int s = i*256 + tid;
    const int mat = s >> 9, tile = (s >> 6) & 7, rr = s & 15, quad = (s >> 4) & 3;
    if (mat == 0 || mat == 3){
      const long row = (long)bm*128 + tile*16 + rr;
      gptr[i] = ((mat == 0) ? Ahi : Alo) + row*(long)K + quad*8;
    } else {
      const long row = (long)bn*128 + tile*16 + rr;
      gptr[i] = ((mat == 1) ? Whi : Wlo) + row*(long)K + quad*8;
    }
  }

  f32x4 acc[4][4];
  #pragma unroll
  for (int a = 0; a < 4; ++a)
    #pragma unroll
    for (int b = 0; b < 4; ++b) acc[a][b] = (f32x4){0.f,0.f,0.f,0.f};

  const int mh = wid & 1, nh = wid >> 1;

  for (int kk = 0; kk < K; kk += 32){
    __syncthreads();
    #pragma unroll
    for (int i = 0; i < 8; ++i)
      GLD_LDS16(gptr[i] + kk, &smem[i*4096 + wid*1024]);
    __syncthreads();
    bf16x8 ah[4], wh_[4], wl_[4], al[4];
    #pragma unroll
    for (int xi = 0; xi < 4; ++xi){
      const int at = mh*4 + xi, wt = nh*4 + xi;
      ah[xi]  = *(const bf16x8*)(&smem[(at*64 + lane)*16]);
      wh_[xi] = *(const bf16x8*)(&smem[8192  + (wt*64 + lane)*16]);
      wl_[xi] = *(const bf16x8*)(&smem[16384 + (wt*64 + lane)*16]);
      al[xi]  = *(const bf16x8*)(&smem[24576 + (at*64 + lane)*16]);
    }
    #pragma unroll
    for (int mi = 0; mi < 4; ++mi)
      #pragma unroll
      for (int ni = 0; ni < 4; ++ni){
        acc[mi][ni] = __builtin_amdgcn_mfma_f32_16x16x32_bf16(ah[mi], wh_[ni], acc[mi][ni], 0,0,0);
        acc[mi][ni] = __builtin_amdgcn_mfma_f32_16x16x32_bf16(ah[mi], wl_[ni], acc[mi][ni], 0,0,0);
        acc[mi][ni] = __builtin_amdgcn_mfma_f32_16x16x32_bf16(al[mi], wh_[ni], acc[mi][ni], 0,0,0);
      }
  }

  const long mbase = (long)bm*128 + mh*64 + (lane >> 4)*4;
  const int  nb    = bn*128 + nh*64 + (lane & 15);
  #pragma unroll
  for (int ni = 0; ni < 4; ++ni){
    const float bv = bias[nb + ni*16];
    #pragma unroll
    for (int mi = 0; mi < 4; ++mi)
      #pragma unroll
      for (int r = 0; r < 4; ++r)
        C[(mbase + mi*16 + r)*2048 + nb + ni*16] = (_Float16)(acc[mi][ni][r] + bv);
  }
}

// -------------------------------------------- fused persistent 2-layer LSTM
// 64 blocks x 512 threads (8 waves). Blocks 0-31: layer 0 (j=blockIdx);
// blocks 32-63: layer 1 (j=blockIdx-32). Wave w: gate g=w>>1, K-half kh=w&1.
// h state: one u32 per element, [slot][j][b][16]:
//   word = bf16(h)<<16 | ((bf16(h) ^ tag) & 0xffff)
// Flags (hints): ready0[t][j] / ready1[t][j], 64B-strided.
__global__ __launch_bounds__(512, 1) void lstm_fused(
    const _Float16* __restrict__ xp,             // [(b,t)][(g,o)]
    const u16* __restrict__ Wh0hi, const u16* __restrict__ Wh0lo,
    const u16* __restrict__ Wh1hi, const u16* __restrict__ Wh1lo,
    const u16* __restrict__ Wx1hi, const u16* __restrict__ Wx1lo,
    const float* __restrict__ bs1,
    uint32_t* __restrict__ h0hisT,               // [1025][16384] u32
    uint32_t* __restrict__ ringT,                // [4][16384] u32
    float* __restrict__ hfin,                    // [32][512] fp32
    uint32_t* __restrict__ ready0,               // [1024][32] flags, FSTR u32
    uint32_t* __restrict__ ready1)               // [1025][32] flags, FSTR u32
{
  __shared__ char asmem0[32768];                 // 32 rows x 1KB (r = cg*2+mt)
  __shared__ char asmem1[32768];
  __shared__ float gsmem[8][32][16];
  const int tid = threadIdx.x;
  const int lane = tid & 63;
  const int wid = tid >> 6;                      // wave 0..7
  const int g   = wid >> 1;                      // gate (0=G,1=I,2=F,3=O)
  const int kh  = wid & 1;                       // K half
  const int role = blockIdx.x >> 5;
  const int j = blockIdx.x & 31;                 // o-slice

  // gather source offsets (u64 units within a 16384-word slot):
  // LDS row r=wid*4+i -> (cg=r>>1, mt=r&1); lane l: b=mt*16+(l&15), lq=l>>4;
  // elem0 = (cg*2+(lq>>1))*512 + b*16 + (lq&1)*8 -> 4 u64 at (elem0>>1)+0..3.
  int f64off[4];
  #pragma unroll
  for (int i = 0; i < 4; ++i){
    const int r = wid*4 + i, cg = r >> 1, mt = r & 1;
    const int bb = mt*16 + (lane & 15);
    const int lq = lane >> 4;
    const int elem0 = (cg*2 + (lq >> 1))*512 + bb*16 + (lq & 1)*8;
    f64off[i] = elem0 >> 1;
  }
  char* const ldst0 = &asmem0[(wid*4)*1024 + lane*16];
  char* const ldst1 = &asmem1[(wid*4)*1024 + lane*16];

  const int b  = tid >> 4, oi = tid & 15;        // per-thread (b, o) cell
  const int og = j*16 + oi;
  const int hoffT = j*512 + b*16 + oi;           // u32 store slot
  float cst = 0.f;

  if (role == 0){
    // ---- layer 0: gates = xp[t] + Wh0 * h0[t-1] ----
    bf16x8 wfh[8], wfl[8];
    {
      const long nrow = g*512 + j*16 + (lane & 15);
      const int kq = (lane >> 4) * 8;
      #pragma unroll
      for (int c = 0; c < 8; ++c){
        const int cg = kh*8 + c;
        wfh[c] = *(const bf16x8*)(Wh0hi + nrow*512 + cg*32 + kq);
        wfl[c] = *(const bf16x8*)(Wh0lo + nrow*512 + cg*32 + kq);
      }
    }
    const long xq = ((long)b << 10)*2048 + j*16 + oi;

    for (int t = 0; t < TSEQ; ++t){
      float xv[4];
      {
        const long base = xq + (long)t*2048;
        #pragma unroll
        for (int gg = 0; gg < 4; ++gg)
          xv[gg] = (float)__builtin_nontemporal_load(xp + base + gg*512);
      }
      if (t > 0){
        if (tid < 64){
          const uint32_t* f = ready0 + ((long)(t-1)*32 + (lane & 31))*FSTR;
          for (;;){
            const uint32_t v = __hip_atomic_load(f, __ATOMIC_RELAXED,
                                                 __HIP_MEMORY_SCOPE_AGENT);
            if (__all(v != 0)) break;
          }
        }
        __syncthreads();
      }
      { // gather h0[t-1] (slot t, tag t+1): tag-verified -> asmem0
        const uint64_t* s = (const uint64_t*)(h0hisT + (size_t)t*16384);
        const uint32_t mag = (uint32_t)t + 1u;
        uint64_t v[16];
        for (;;){
          #pragma unroll
          for (int i = 0; i < 4; ++i)
            #pragma unroll
            for (int e = 0; e < 4; ++e)
              v[i*4+e] = __hip_atomic_load(s + f64off[i] + e, __ATOMIC_RELAXED,
                                           __HIP_MEMORY_SCOPE_AGENT);
          uint32_t bad = 0;
          #pragma unroll
          for (int q = 0; q < 16; ++q){
            const uint32_t w0 = (uint32_t)v[q], w1 = (uint32_t)(v[q] >> 32);
            bad |= (((w0 >> 16) ^ w0) ^ mag) | (((w1 >> 16) ^ w1) ^ mag);
          }
          if ((bad & 0xffffu) == 0) break;
          __builtin_amdgcn_s_sleep(1);
        }
        #pragma unroll
        for (int i = 0; i < 4; ++i){
          bf16x8 o;
          #pragma unroll
          for (int e = 0; e < 4; ++e){
            o[2*e]   = (short)(u16)(((uint32_t)v[i*4+e]) >> 16);
            o[2*e+1] = (short)(u16)((uint32_t)(v[i*4+e] >> 48));
          }
          *(bf16x8*)(ldst0 + i*1024) = o;
        }
      }
      __syncthreads();

      f32x4 acc0 = {0.f,0.f,0.f,0.f}, acc1 = {0.f,0.f,0.f,0.f};
      #pragma unroll
      for (int c = 0; c < 8; ++c){
        const int cg = kh*8 + c;
        bf16x8 a0 = *(const bf16x8*)(&asmem0[((cg*2 + 0)*64 + lane)*16]);
        bf16x8 a1 = *(const bf16x8*)(&asmem0[((cg*2 + 1)*64 + lane)*16]);
        acc0 = __builtin_amdgcn_mfma_f32_16x16x32_bf16(a0, wfh[c], acc0, 0,0,0);
        acc1 = __builtin_amdgcn_mfma_f32_16x16x32_bf16(a1, wfh[c], acc1, 0,0,0);
        acc0 = __builtin_amdgcn_mfma_f32_16x16x32_bf16(a0, wfl[c], acc0, 0,0,0);
        acc1 = __builtin_amdgcn_mfma_f32_16x16x32_bf16(a1, wfl[c], acc1, 0,0,0);
      }
      {
        const int bq = (lane >> 4) * 4, ci = lane & 15;
        #pragma unroll
        for (int r = 0; r < 4; ++r){
          gsmem[wid][bq + r][ci]      = acc0[r];
          gsmem[wid][16 + bq + r][ci] = acc1[r];
        }
      }
      __syncthreads();
      {
        const float gv = ftanh_(gsmem[0][b][oi] + gsmem[1][b][oi] + xv[0]);
        const float iv = fsig (gsmem[2][b][oi] + gsmem[3][b][oi] + xv[1]);
        const float fv = fsig (gsmem[4][b][oi] + gsmem[5][b][oi] + xv[2]);
        const float ov = fsig (gsmem[6][b][oi] + gsmem[7][b][oi] + xv[3]);
        cst = fv*cst + iv*gv;
        const float hv = ov * ftanh_(cst);
        const u16 hh = f2bf(hv);
        const uint32_t wrd = ((uint32_t)hh << 16) |
                             ((hh ^ ((uint32_t)t + 2u)) & 0xffffu);
        __hip_atomic_store(h0hisT + (size_t)(t+1)*16384 + hoffT, wrd,
                           __ATOMIC_RELAXED, __HIP_MEMORY_SCOPE_AGENT);
      }
      // raw barrier (no implicit vmcnt drain) purely to order the flag hint
      // after all waves ISSUED their h stores; tags cover in-flight stores.
      __builtin_amdgcn_s_barrier();
      if (tid == 0)
        __hip_atomic_store(ready0 + ((long)t*32 + j)*FSTR, 1u,
                           __ATOMIC_RELAXED, __HIP_MEMORY_SCOPE_AGENT);
    }
  } else {
    // ---- layer 1: gates = bs1 + Wx1*h0[t] + Wh1*h1[t-1] ----
    bf16x8 wfh[8], wfl[8], wxh[8], wxl[8];
    {
      const long nrow = g*512 + j*16 + (lane & 15);
      const int kq = (lane >> 4) * 8;
      #pragma unroll
      for (int c = 0; c < 8; ++c){
        const int cg = kh*8 + c;
        wfh[c] = *(const bf16x8*)(Wh1hi + nrow*512 + cg*32 + kq);
        wfl[c] = *(const bf16x8*)(Wh1lo + nrow*512 + cg*32 + kq);
        wxh[c] = *(const bf16x8*)(Wx1hi + nrow*512 + cg*32 + kq);
        wxl[c] = *(const bf16x8*)(Wx1lo + nrow*512 + cg*32 + kq);
      }
    }
    float bv[4];
    #pragma unroll
    for (int gg = 0; gg < 4; ++gg) bv[gg] = bs1[gg*512 + og];

    for (int t = 0; t < TSEQ; ++t){
      if (tid < 64){
        // lanes 0..31: h0[t] flags; lanes 32..63: h1[t-1] flags
        const uint32_t* f = (lane < 32)
            ? (ready0 + ((long)t*32 + lane)*FSTR)
            : (ready1 + ((long)t*32 + (lane - 32))*FSTR);
        for (;;){
          const uint32_t v = __hip_atomic_load(f, __ATOMIC_RELAXED,
                                               __HIP_MEMORY_SCOPE_AGENT);
          if (__all(v != 0)) break;
        }
      }
      __syncthreads();
      { // h0[t] (slot t+1, tag t+2) -> asmem0 (L0 runs ahead; ~1 sweep)
        const uint64_t* s0 = (const uint64_t*)(h0hisT + (size_t)(t+1)*16384);
        const uint32_t mag0 = (uint32_t)t + 2u;
        uint64_t v[16];
        for (;;){
          #pragma unroll
          for (int i = 0; i < 4; ++i)
            #pragma unroll
            for (int e = 0; e < 4; ++e)
              v[i*4+e] = __hip_atomic_load(s0 + f64off[i] + e, __ATOMIC_RELAXED,
                                           __HIP_MEMORY_SCOPE_AGENT);
          uint32_t bad = 0;
          #pragma unroll
          for (int q = 0; q < 16; ++q){
            const uint32_t w0 = (uint32_t)v[q], w1 = (uint32_t)(v[q] >> 32);
            bad |= (((w0 >> 16) ^ w0) ^ mag0) | (((w1 >> 16) ^ w1) ^ mag0);
          }
          if ((bad & 0xffffu) == 0) break;
          __builtin_amdgcn_s_sleep(1);
        }
        #pragma unroll
        for (int i = 0; i < 4; ++i){
          bf16x8 o;
          #pragma unroll
          for (int e = 0; e < 4; ++e){
            o[2*e]   = (short)(u16)(((uint32_t)v[i*4+e]) >> 16);
            o[2*e+1] = (short)(u16)((uint32_t)(v[i*4+e] >> 48));
          }
          *(bf16x8*)(ldst0 + i*1024) = o;
        }
      }
      { // h1[t-1] (ring slot (t+3)&3, tag t+6) -> asmem1
        const uint64_t* s1 = (const uint64_t*)(ringT + (size_t)((t+3)&3)*16384);
        const uint32_t mag1 = (uint32_t)t + 6u;
        uint64_t v[16];
        for (;;){
          #pragma unroll
          for (int i = 0; i < 4; ++i)
            #pragma unroll
            for (int e = 0; e < 4; ++e)
              v[i*4+e] = __hip_atomic_load(s1 + f64off[i] + e, __ATOMIC_RELAXED,
                                           __HIP_MEMORY_SCOPE_AGENT);
          uint32_t bad = 0;
          #pragma unroll
          for (int q = 0; q < 16; ++q){
            const uint32_t w0 = (uint32_t)v[q], w1 = (uint32_t)(v[q] >> 32);
            bad |= (((w0 >> 16) ^ w0) ^ mag1) | (((w1 >> 16) ^ w1) ^ mag1);
          }
          if ((bad & 0xffffu) == 0) break;
          __builtin_amdgcn_s_sleep(1);
        }
        #pragma unroll
        for (int i = 0; i < 4; ++i){
          bf16x8 o;
          #pragma unroll
          for (int e = 0; e < 4; ++e){
            o[2*e]   = (short)(u16)(((uint32_t)v[i*4+e]) >> 16);
            o[2*e+1] = (short)(u16)((uint32_t)(v[i*4+e] >> 48));
          }
          *(bf16x8*)(ldst1 + i*1024) = o;
        }
      }
      __syncthreads();

      f32x4 acc0 = {0.f,0.f,0.f,0.f}, acc1 = {0.f,0.f,0.f,0.f};
      #pragma unroll
      for (int c = 0; c < 8; ++c){
        const int cg = kh*8 + c;
        bf16x8 h1a0 = *(const bf16x8*)(&asmem1[((cg*2 + 0)*64 + lane)*16]);
        bf16x8 h1a1 = *(const bf16x8*)(&asmem1[((cg*2 + 1)*64 + lane)*16]);
        acc0 = __builtin_amdgcn_mfma_f32_16x16x32_bf16(h1a0, wfh[c], acc0, 0,0,0);
        acc1 = __builtin_amdgcn_mfma_f32_16x16x32_bf16(h1a1, wfh[c], acc1, 0,0,0);
        acc0 = __builtin_amdgcn_mfma_f32_16x16x32_bf16(h1a0, wfl[c], acc0, 0,0,0);
        acc1 = __builtin_amdgcn_mfma_f32_16x16x32_bf16(h1a1, wfl[c], acc1, 0,0,0);
        bf16x8 h0a0 = *(const bf16x8*)(&asmem0[((cg*2 + 0)*64 + lane)*16]);
        bf16x8 h0a1 = *(const bf16x8*)(&asmem0[((cg*2 + 1)*64 + lane)*16]);
        acc0 = __builtin_amdgcn_mfma_f32_16x16x32_bf16(h0a0, wxh[c], acc0, 0,0,0);
        acc1 = __builtin_amdgcn_mfma_f32_16x16x32_bf16(h0a1, wxh[c], acc1, 0,0,0);
        acc0 = __builtin_amdgcn_mfma_f32_16x16x32_bf16(h0a0, wxl[c], acc0, 0,0,0);
        acc1 = __builtin_amdgcn_mfma_f32_16x16x32_bf16(h0a1, wxl[c], acc1, 0,0,0);
      }
      {
        const int bq = (lane >> 4) * 4, ci = lane & 15;
        #pragma unroll
        for (int r = 0; r < 4; ++r){
          gsmem[wid][bq + r][ci]      = acc0[r];
          gsmem[wid][16 + bq + r][ci] = acc1[r];
        }
      }
      __syncthreads();
      {
        const float gv = ftanh_(gsmem[0][b][oi] + gsmem[1][b][oi] + bv[0]);
        const float iv = fsig (gsmem[2][b][oi] + gsmem[3][b][oi] + bv[1]);
        const float fv = fsig (gsmem[4][b][oi] + gsmem[5][b][oi] + bv[2]);
        const float ov = fsig (gsmem[6][b][oi] + gsmem[7][b][oi] + bv[3]);
        cst = fv*cst + iv*gv;
        const float hv = ov * ftanh_(cst);
        if (t == TSEQ-1) hfin[b*512 + og] = hv;
        const u16 hh = f2bf(hv);
        const uint32_t wrd = ((uint32_t)hh << 16) |
                             ((hh ^ ((uint32_t)t + 7u)) & 0xffffu);
        __hip_atomic_store(ringT + (size_t)(t&3)*16384 + hoffT, wrd,
                           __ATOMIC_RELAXED, __HIP_MEMORY_SCOPE_AGENT);
      }
      __builtin_amdgcn_s_barrier();
      if (tid == 0)
        __hip_atomic_store(ready1 + ((long)(t+1)*32 + j)*FSTR, 1u,
                           __ATOMIC_RELAXED, __HIP_MEMORY_SCOPE_AGENT);
    }
  }
}

// ------------------------------------------------------------------- FC out
__global__ void fc_kernel(const float* __restrict__ hfin,
                          const float* __restrict__ fcW, const float* __restrict__ fcb,
                          float* __restrict__ out)
{
  __shared__ float hbufs[512];
  const int b = blockIdx.x, tid = threadIdx.x;
  for (int i = tid; i < 512; i += 256)
    hbufs[i] = hfin[b*512 + i];
  __syncthreads();
  float acc = fcb[tid];
  const float4* w4 = (const float4*)(fcW + tid*512);
  #pragma unroll 8
  for (int k = 0; k < 128; ++k){
    const float4 w = w4[k];
    acc += hbufs[4*k]*w.x + hbufs[4*k+1]*w.y + hbufs[4*k+2]*w.z + hbufs[4*k+3]*w.w;
  }
  out[b*256 + tid] = acc;
}

// ---------------------------------------------------------------- launcher
extern "C" void kernel_launch(void* const* d_in, const int* in_sizes, int n_in,
                              void* d_out, int out_size, void* d_ws, size_t ws_size,
                              hipStream_t stream)
{
  const float* x   = (const float*)d_in[0];
  const float* Wx0 = (const float*)d_in[1];
  const float* bx0 = (const float*)d_in[2];
  const float* Wh0 = (const float*)d_in[3];
  const float* bh0 = (const float*)d_in[4];
  const float* Wx1 = (const float*)d_in[5];
  const float* bx1 = (const float*)d_in[6];
  const float* Wh1 = (const float*)d_in[7];
  const float* bh1 = (const float*)d_in[8];
  const float* fcW = (const float*)d_in[9];
  const float* fcb = (const float*)d_in[10];

  char* ws = (char*)d_ws;
  size_t off = 0;
  auto take = [&](size_t sz){ void* p = ws + off; off += sz; return p; };
  _Float16* xp     = (_Float16*)take((size_t)32768*2048*2);    // 128 MiB
  uint32_t* h0hisT = (uint32_t*)take((size_t)1025*16384*4);    // 67.2 MB h0 history
  u16*   xh      = (u16*)take((size_t)8388608*2);
  u16*   xl      = (u16*)take((size_t)8388608*2);
  u16*   wx0h    = (u16*)take((size_t)524288*2);
  u16*   wx0l    = (u16*)take((size_t)524288*2);
  u16*   wh0h    = (u16*)take((size_t)1048576*2);
  u16*   wh0l    = (u16*)take((size_t)1048576*2);
  u16*   wx1h    = (u16*)take((size_t)1048576*2);
  u16*   wx1l    = (u16*)take((size_t)1048576*2);
  u16*   wh1h    = (u16*)take((size_t)1048576*2);
  u16*   wh1l    = (u16*)take((size_t)1048576*2);
  uint32_t* ringT = (uint32_t*)take((size_t)4*16384*4);        // 256 KB h1 ring
  float* hfin    = (float*)take((size_t)32*512*4);
  float* bs0     = (float*)take(2048*4);
  float* bs1     = (float*)take(2048*4);
  uint32_t* ready0 = (uint32_t*)take((size_t)1024*32*FSTR*4);  // 2 MiB flags L0
  uint32_t* ready1 = (uint32_t*)take((size_t)1025*32*FSTR*4);  // 2 MiB flags L1
  (void)in_sizes; (void)n_in; (void)out_size; (void)ws_size;

  // tag/flag hygiene: unwritten words must fail checks every launch/replay
  (void)hipMemsetAsync(h0hisT, 0, (size_t)1025*16384*4, stream);
  (void)hipMemsetAsync(ringT,  0, (size_t)4*16384*4, stream);
  (void)hipMemsetAsync(ready0, 0, (size_t)1024*32*FSTR*4, stream);
  (void)hipMemsetAsync(ready1, 0, (size_t)1025*32*FSTR*4, stream);

  split_f32<<<4096,256,0,stream>>>(x,   xh,   xl,   8388608);
  split_f32<<<1024,256,0,stream>>>(Wx0, wx0h, wx0l, 524288);
  split_f32<<<2048,256,0,stream>>>(Wh0, wh0h, wh0l, 1048576);
  split_f32<<<2048,256,0,stream>>>(Wx1, wx1h, wx1l, 1048576);
  split_f32<<<2048,256,0,stream>>>(Wh1, wh1h, wh1l, 1048576);
  vec_add<<<8,256,0,stream>>>(bx0, bh0, bs0, 2048);
  vec_add<<<8,256,0,stream>>>(bx1, bh1, bs1, 2048);
  init_state<<<64,256,0,stream>>>(h0hisT, ringT, ready1);

  dim3 gg(16, 256);
  gemm_split<<<gg,256,0,stream>>>(xh, xl, wx0h, wx0l, bs0, xp, 256);
  lstm_fused<<<64,512,0,stream>>>(xp, wh0h, wh0l, wh1h, wh1l, wx1h, wx1l, bs1,
                                  h0hisT, ringT, hfin, ready0, ready1);
  fc_kernel<<<32,256,0,stream>>>(hfin, fcW, fcb, (float*)d_out);
}

// Round 6
// 4050.579 us; speedup vs baseline: 2.1120x; 1.8003x over previous
//
#include <hip/hip_runtime.h>
#include <hip/hip_bf16.h>
#include <stdint.h>

// 2-layer LSTM, B=32 T=1024 D=256 H=512, fc -> 256.
// R14 = R13's XCD-local idea, de-risked:
//  - 256 blocks; role = bid%8 (0 -> L0, 1 -> L1, else exit). m157's verified
//    round-robin mapping puts each layer's 32 workers on ONE XCD.
//  - XCC_ID via __builtin_amdgcn_s_getreg(6164) (no asm syntax risk).
//  - ALL spins bounded or fall back to R9's proven agent-scope protocol:
//    verify poll bounded -> safe mode; per-step local poll bounded -> mixed
//    loop incl. agent flags + permanent demotion. Producers always write
//    both legs (XCD-local ring + agent mirror), so either leg is valid.
//  - early local flag: [local stores; vmcnt(1); barrier; local flag;
//    vmcnt(0); barrier; agent flag] - local flag skips the agent drain.
//  - L1 prefetches h0[t+1] (agent) in the step tail; L0 runs ahead so the
//    poll passes instantly -> cross-XCD hop off L1's critical path.
// Kept lessons: sc0 on every poll/re-read (R10), polls stay 64-lane narrow
// (R11/R12), asm load macros in R9's proven 8-operand shape only.

typedef __attribute__((ext_vector_type(8))) short bf16x8;
typedef __attribute__((ext_vector_type(4))) float f32x4;
typedef __attribute__((ext_vector_type(4))) unsigned int u32x4;
typedef unsigned short u16;

#define TSEQ 1024
#define FSTR 16        // flag stride in u32 units (64B)
#define LPOLL 1024     // per-step local poll bound
#define VPOLL (1<<16)  // placement-verify poll bound

static __device__ __forceinline__ float fsig(float x){ return 1.0f/(1.0f+__expf(-x)); }
static __device__ __forceinline__ float ftanh_(float x){ return 2.0f/(1.0f+__expf(-2.0f*x)) - 1.0f; }
static __device__ __forceinline__ u16 f2bf(float v){
  __hip_bfloat16 b = __float2bfloat16(v);
  return *reinterpret_cast<u16*>(&b);
}
static __device__ __forceinline__ float bf2f(u16 u){
  __hip_bfloat16 b; *reinterpret_cast<u16*>(&b) = u;
  return __bfloat162float(b);
}

// async global->LDS, 16B per lane (GEMM staging)
#define GLD_LDS16(g, l) \
  __builtin_amdgcn_global_load_lds((const __attribute__((address_space(1))) uint32_t*)(g), \
                                   (__attribute__((address_space(3))) uint32_t*)(l), 16, 0, 0)

// L1-bypassing (XCD-L2-coherent) flag load
static __device__ __forceinline__ uint32_t ld_flag_sc0(const uint32_t* p){
  uint32_t v;
  asm volatile("global_load_dword %0, %1, off sc0\n\ts_waitcnt vmcnt(0)"
               : "=v"(v) : "v"(p) : "memory");
  return v;
}
static __device__ __forceinline__ uint32_t ld_ag(const uint32_t* p){
  return __hip_atomic_load(p, __ATOMIC_RELAXED, __HIP_MEMORY_SCOPE_AGENT);
}
static __device__ __forceinline__ void st_wg(uint32_t* p, uint32_t v){
  __hip_atomic_store(p, v, __ATOMIC_RELAXED, __HIP_MEMORY_SCOPE_WORKGROUP);
}
static __device__ __forceinline__ void st_ag(uint32_t* p, uint32_t v){
  __hip_atomic_store(p, v, __ATOMIC_RELAXED, __HIP_MEMORY_SCOPE_AGENT);
}

// 4 pipelined 16B loads, XCD-L2-local flavor (sc0: bypass L1 only)
#define LOAD4_SC0(P0,P1,P2,P3, R0,R1,R2,R3)                                    \
  asm volatile(                                                                \
    "global_load_dwordx4 %0, %4, off sc0\n\t"                                  \
    "global_load_dwordx4 %1, %5, off sc0\n\t"                                  \
    "global_load_dwordx4 %2, %6, off sc0\n\t"                                  \
    "global_load_dwordx4 %3, %7, off sc0"                                      \
    : "=&v"(R0),"=&v"(R1),"=&v"(R2),"=&v"(R3)                                  \
    : "v"(P0),"v"(P1),"v"(P2),"v"(P3)                                          \
    : "memory")

// agent flavor (sc0 sc1: MALL-fresh) - R9's proven shape
#define LOAD4_AG(P0,P1,P2,P3, R0,R1,R2,R3)                                     \
  asm volatile(                                                                \
    "global_load_dwordx4 %0, %4, off sc0 sc1\n\t"                              \
    "global_load_dwordx4 %1, %5, off sc0 sc1\n\t"                              \
    "global_load_dwordx4 %2, %6, off sc0 sc1\n\t"                              \
    "global_load_dwordx4 %3, %7, off sc0 sc1"                                  \
    : "=&v"(R0),"=&v"(R1),"=&v"(R2),"=&v"(R3)                                  \
    : "v"(P0),"v"(P1),"v"(P2),"v"(P3)                                          \
    : "memory")

#define VM_DRAIN asm volatile("s_waitcnt vmcnt(0)" ::: "memory")
#define VM_WAIT1 asm volatile("s_waitcnt vmcnt(1)" ::: "memory")
#define CFENCE   asm volatile("" ::: "memory")

// ---------------------------------------------------------------- utilities
__global__ void split_f32(const float* __restrict__ src, u16* __restrict__ hi,
                          u16* __restrict__ lo, const int n)
{
  for (int i = blockIdx.x*blockDim.x + threadIdx.x; i < n; i += gridDim.x*blockDim.x){
    const float v = src[i];
    const u16 h = f2bf(v);
    hi[i] = h;
    lo[i] = f2bf(v - bf2f(h));
  }
}

__global__ void vec_add(const float* __restrict__ a, const float* __restrict__ b,
                        float* __restrict__ c, const int n)
{
  const int i = blockIdx.x*blockDim.x + threadIdx.x;
  if (i < n) c[i] = a[i] + b[i];
}

// zero h0his slot 0, ring0loc slot 0, ring1loc/ring1rem slot 3
__global__ void init_state(uint32_t* h0his, uint32_t* ring0loc,
                           uint32_t* ring1loc, uint32_t* ring1rem)
{
  const int i = blockIdx.x*256 + threadIdx.x;       // 8192 = 32*256
  h0his[i] = 0;
  ring0loc[i] = 0;
  ring1loc[3*8192 + i] = 0;
  ring1rem[3*8192 + i] = 0;
}

// ------------------------------------------------------ split-bf16 MFMA GEMM
// xproj0: C[m][n] = sum_k A[m][k]*W[n][k] + bias[n], M=32768 N=2048 K=256
// 3-term split-bf16: Ah*Wh + Ah*Wl + Al*Wh. Output fp16. (R5-proven, verbatim)
__global__ __launch_bounds__(256, 2) void gemm_split(
    const u16* __restrict__ Ahi, const u16* __restrict__ Alo,
    const u16* __restrict__ Whi, const u16* __restrict__ Wlo,
    const float* __restrict__ bias, _Float16* __restrict__ C,
    const int K)
{
  __shared__ char smem[32768];
  const int tid = threadIdx.x, lane = tid & 63, wid = tid >> 6;
  const int bn = blockIdx.x, bm = blockIdx.y;

  const u16* gptr[8];
  #pragma unroll
  for (int i = 0; i < 8; ++i){
    const int s = i*256 + tid;
    const int mat = s >> 9, tile = (s >> 6) & 7, rr = s & 15, quad = (s >> 4) & 3;
    if (mat == 0 || mat == 3){
      const long row = (long)bm*128 + tile*16 + rr;
      gptr[i] = ((mat == 0) ? Ahi : Alo) + row*(long)K + quad*8;
    } else {
      const long row = (long)bn*128 + tile*16 + rr;
      gptr[i] = ((mat == 1) ? Whi : Wlo) + row*(long)K + quad*8;
    }
  }

  f32x4 acc[4][4];
  #pragma unroll
  for (int a = 0; a < 4; ++a)
    #pragma unroll
    for (int b = 0; b < 4; ++b) acc[a][b] = (f32x4){0.f,0.f,0.f,0.f};

  const int mh = wid & 1, nh = wid >> 1;

  for (int kk = 0; kk < K; kk += 32){
    __syncthreads();
    #pragma unroll
    for (int i = 0; i < 8; ++i)
      GLD_LDS16(gptr[i] + kk, &smem[i*4096 + wid*1024]);
    __syncthreads();
    bf16x8 ah[4], wh_[4], wl_[4], al[4];
    #pragma unroll
    for (int xi = 0; xi < 4; ++xi){
      const int at = mh*4 + xi, wt = nh*4 + xi;
      ah[xi]  = *(const bf16x8*)(&smem[(at*64 + lane)*16]);
      wh_[xi] = *(const bf16x8*)(&smem[8192  + (wt*64 + lane)*16]);
      wl_[xi] = *(const bf16x8*)(&smem[16384 + (wt*64 + lane)*16]);
      al[xi]  = *(const bf16x8*)(&smem[24576 + (at*64 + lane)*16]);
    }
    #pragma unroll
    for (int mi = 0; mi < 4; ++mi)
      #pragma unroll
      for (int ni = 0; ni < 4; ++ni){
        acc[mi][ni] = __builtin_amdgcn_mfma_f32_16x16x32_bf16(ah[mi], wh_[ni], acc[mi][ni], 0,0,0);
        acc[mi][ni] = __builtin_amdgcn_mfma_f32_16x16x32_bf16(ah[mi], wl_[ni], acc[mi][ni], 0,0,0);
        acc[mi][ni] = __builtin_amdgcn_mfma_f32_16x16x32_bf16(al[mi], wh_[ni], acc[mi][ni], 0,0,0);
      }
  }

  const long mbase = (long)bm*128 + mh*64 + (lane >> 4)*4;
  const int  nb    = bn*128 + nh*64 + (lane & 15);
  #pragma unroll
  for (int ni = 0; ni < 4; ++ni){
    const float bv = bias[nb + ni*16];
    #pragma unroll
    for (int mi = 0; mi < 4; ++mi)
      #pragma unroll
      for (int r = 0; r < 4; ++r)
        C[(mbase + mi*16 + r)*2048 + nb + ni*16] = (_Float16)(acc[mi][ni][r] + bv);
  }
}

// -------------------------------------------- fused persistent 2-layer LSTM
__global__ __launch_bounds__(512, 1) void lstm_fused(
    const _Float16* __restrict__ xp,             // [(b,t)][(g,o)]
    const u16* __restrict__ Wh0hi, const u16* __restrict__ Wh0lo,
    const u16* __restrict__ Wh1hi, const u16* __restrict__ Wh1lo,
    const u16* __restrict__ Wx1hi, const u16* __restrict__ Wx1lo,
    const float* __restrict__ bs1,
    uint32_t* __restrict__ h0his,                // [1025][8192] u32 (agent leg)
    uint32_t* __restrict__ ring0loc,             // [4][8192] u32 (XCD-local)
    uint32_t* __restrict__ ring1loc,             // [4][8192] u32 (XCD-local)
    uint32_t* __restrict__ ring1rem,             // [4][8192] u32 (agent leg)
    uint32_t* __restrict__ flag0loc,             // [32] FSTR-strided
    uint32_t* __restrict__ flag1loc,
    uint32_t* __restrict__ flag0rem,
    uint32_t* __restrict__ flag1rem,
    uint32_t* __restrict__ xcdbuf,               // [64] FSTR-strided
    float* __restrict__ hfin)                    // [32][512] fp32
{
  const int bid = blockIdx.x;
  const int role = bid & 7;
  if (role > 1) return;                          // non-worker
  const int j = bid >> 3;                        // 0..31 o-slice

  __shared__ char asmem0[32768];                 // 32 rows x 1KB (r = cg*2+mt)
  __shared__ char asmem1[32768];
  __shared__ float gsmem[8][32][16];
  __shared__ int fastSh;                         // own-layer XCD-uniform (demotable)
  __shared__ int useLocSh;                       // this step's gather leg
  const int tid = threadIdx.x;
  const int lane = tid & 63;
  const int wid = tid >> 6;                      // wave 0..7
  const int g   = wid >> 1;                      // gate (0=G,1=I,2=F,3=O)
  const int kh  = wid & 1;                       // K half

  // ---- XCD placement publish + bounded verify ----
  {
    const uint32_t myxcd = (uint32_t)__builtin_amdgcn_s_getreg(6164) & 0xffu; // hwreg 20 (XCC_ID), off 0, sz 4
    if (tid == 0)
      st_ag(xcdbuf + (role*32 + j)*FSTR, myxcd | 0x100u);
    if (wid == 0){
      uint32_t v = 0; int seen = 0;
      for (int it = 0; it < VPOLL; ++it){
        v = ld_ag(xcdbuf + lane*FSTR);
        if (__all((v & 0x100u) != 0)){ seen = 1; break; }
      }
      int uniform = 0;
      if (seen){
        const int vi = (int)(v & 0xffu);
        const int ref = __shfl(vi, role*32);
        const unsigned long long bal = __ballot(vi == ref);
        const unsigned long long seg = (role == 0) ? (bal & 0xffffffffull)
                                                   : (bal >> 32);
        uniform = (seg == 0xffffffffull) ? 1 : 0;
      }
      if (lane == 0) fastSh = uniform;
    }
    __syncthreads();
  }

  // gather source offsets (u32 units within an 8192-u32 slot), rows wid*4+i
  int soff[4];
  #pragma unroll
  for (int i = 0; i < 4; ++i){
    const int r = wid*4 + i, cg = r >> 1, mt = r & 1;
    const int bb = mt*16 + (lane & 15);
    const int q = lane >> 4;
    soff[i] = (cg*2 + (q >> 1))*256 + bb*8 + (q & 1)*4;
  }
  char* const ldst0 = &asmem0[(wid*4)*1024 + lane*16];
  char* const ldst1 = &asmem1[(wid*4)*1024 + lane*16];

  const int b  = tid >> 4, oi = tid & 15;        // per-thread (b, o) cell
  const int og = j*16 + oi;
  const int hoff = j*256 + b*8 + (oi >> 1);      // u32 store slot (even oi)
  float cst = 0.f;

  if (role == 0){
    // ---- layer 0: gates = xp[t] + Wh0 * h0[t-1] ----
    bf16x8 wfh[8], wfl[8];
    {
      const long nrow = g*512 + j*16 + (lane & 15);
      const int kq = (lane >> 4) * 8;
      #pragma unroll
      for (int c = 0; c < 8; ++c){
        const int cg = kh*8 + c;
        wfh[c] = *(const bf16x8*)(Wh0hi + nrow*512 + cg*32 + kq);
        wfl[c] = *(const bf16x8*)(Wh0lo + nrow*512 + cg*32 + kq);
      }
    }
    const long xq = ((long)b << 10)*2048 + j*16 + oi;

    for (int t = 0; t < TSEQ; ++t){
      float xv[4];
      {
        const long base = xq + (long)t*2048;
        #pragma unroll
        for (int gg = 0; gg < 4; ++gg)
          xv[gg] = (float)__builtin_nontemporal_load(xp + base + gg*512);
      }
      if (t > 0){
        if (tid < 64){
          int useL = 0;
          const uint32_t thr = (uint32_t)t;
          const uint32_t* fl = flag0loc + (lane & 31)*FSTR;
          const uint32_t* fr = flag0rem + (lane & 31)*FSTR;
          if (fastSh){
            for (int it = 0; it < LPOLL; ++it)
              if (__all(ld_flag_sc0(fl) >= thr)){ useL = 1; break; }
          }
          if (!useL){
            for (;;){
              if (fastSh && __all(ld_flag_sc0(fl) >= thr)){ useL = 1; break; }
              if (__all(ld_ag(fr) >= thr)) break;
            }
            if (lane == 0 && !useL) fastSh = 0;   // demote: local leg unusable
          }
          if (lane == 0) useLocSh = useL;
        }
        __syncthreads();
      } else {
        if (tid == 0) useLocSh = 0;
        __syncthreads();
      }
      if (useLocSh){ // stage h0[t-1] from XCD-local ring
        const uint32_t* s = ring0loc + (size_t)(t & 3)*8192;
        u32x4 r0,r1,r2,r3;
        LOAD4_SC0(s+soff[0], s+soff[1], s+soff[2], s+soff[3], r0,r1,r2,r3);
        VM_DRAIN;
        *(u32x4*)(ldst0+0*1024)=r0; *(u32x4*)(ldst0+1*1024)=r1;
        *(u32x4*)(ldst0+2*1024)=r2; *(u32x4*)(ldst0+3*1024)=r3;
      } else {       // stage from agent history (R9 path)
        const uint32_t* s = h0his + (size_t)t*8192;
        u32x4 r0,r1,r2,r3;
        LOAD4_AG(s+soff[0], s+soff[1], s+soff[2], s+soff[3], r0,r1,r2,r3);
        VM_DRAIN;
        *(u32x4*)(ldst0+0*1024)=r0; *(u32x4*)(ldst0+1*1024)=r1;
        *(u32x4*)(ldst0+2*1024)=r2; *(u32x4*)(ldst0+3*1024)=r3;
      }
      __syncthreads();

      f32x4 acc0 = {0.f,0.f,0.f,0.f}, acc1 = {0.f,0.f,0.f,0.f};
      #pragma unroll
      for (int c = 0; c < 8; ++c){
        const int cg = kh*8 + c;
        bf16x8 a0 = *(const bf16x8*)(&asmem0[((cg*2 + 0)*64 + lane)*16]);
        bf16x8 a1 = *(const bf16x8*)(&asmem0[((cg*2 + 1)*64 + lane)*16]);
        acc0 = __builtin_amdgcn_mfma_f32_16x16x32_bf16(a0, wfh[c], acc0, 0,0,0);
        acc1 = __builtin_amdgcn_mfma_f32_16x16x32_bf16(a1, wfh[c], acc1, 0,0,0);
        acc0 = __builtin_amdgcn_mfma_f32_16x16x32_bf16(a0, wfl[c], acc0, 0,0,0);
        acc1 = __builtin_amdgcn_mfma_f32_16x16x32_bf16(a1, wfl[c], acc1, 0,0,0);
      }
      {
        const int bq = (lane >> 4) * 4, ci = lane & 15;
        #pragma unroll
        for (int r = 0; r < 4; ++r){
          gsmem[wid][bq + r][ci]      = acc0[r];
          gsmem[wid][16 + bq + r][ci] = acc1[r];
        }
      }
      __syncthreads();
      {
        const float gv = ftanh_(gsmem[0][b][oi] + gsmem[1][b][oi] + xv[0]);
        const float iv = fsig (gsmem[2][b][oi] + gsmem[3][b][oi] + xv[1]);
        const float fv = fsig (gsmem[4][b][oi] + gsmem[5][b][oi] + xv[2]);
        const float ov = fsig (gsmem[6][b][oi] + gsmem[7][b][oi] + xv[3]);
        cst = fv*cst + iv*gv;
        const float hv = ov * ftanh_(cst);
        const u16 hh = f2bf(hv);
        const int po = __shfl_xor((int)hh, 1, 64);
        if ((oi & 1) == 0){
          const uint32_t p = (uint32_t)hh | ((uint32_t)(po & 0xffff) << 16);
          st_wg(ring0loc + (size_t)((t+1) & 3)*8192 + hoff, p);  // local leg FIRST
          CFENCE;
          st_ag(h0his + (size_t)(t+1)*8192 + hoff, p);           // agent leg
        }
      }
      // early local flag: local data retired (in-order vmcnt) before flag
      VM_WAIT1;
      __builtin_amdgcn_s_barrier();
      if (tid == 0) st_wg(flag0loc + j*FSTR, (uint32_t)(t+1));
      VM_DRAIN;
      __builtin_amdgcn_s_barrier();
      if (tid == 0) st_ag(flag0rem + j*FSTR, (uint32_t)(t+1));
    }
  } else {
    // ---- layer 1: gates = bs1 + Wx1*h0[t] + Wh1*h1[t-1] ----
    bf16x8 wfh[8], wfl[8], wxh[8], wxl[8];
    {
      const long nrow = g*512 + j*16 + (lane & 15);
      const int kq = (lane >> 4) * 8;
      #pragma unroll
      for (int c = 0; c < 8; ++c){
        const int cg = kh*8 + c;
        wfh[c] = *(const bf16x8*)(Wh1hi + nrow*512 + cg*32 + kq);
        wfl[c] = *(const bf16x8*)(Wh1lo + nrow*512 + cg*32 + kq);
        wxh[c] = *(const bf16x8*)(Wx1hi + nrow*512 + cg*32 + kq);
        wxl[c] = *(const bf16x8*)(Wx1lo + nrow*512 + cg*32 + kq);
      }
    }
    float bv[4];
    #pragma unroll
    for (int gg = 0; gg < 4; ++gg) bv[gg] = bs1[gg*512 + og];

    // prologue: prefetch h0[0] (slot 1, agent) into asmem0
    {
      if (tid < 64){
        const uint32_t* fr = flag0rem + (lane & 31)*FSTR;
        while (!__all(ld_ag(fr) >= 1u)) {}
      }
      __syncthreads();
      const uint32_t* s0 = h0his + (size_t)1*8192;
      u32x4 r0,r1,r2,r3;
      LOAD4_AG(s0+soff[0], s0+soff[1], s0+soff[2], s0+soff[3], r0,r1,r2,r3);
      VM_DRAIN;
      *(u32x4*)(ldst0+0*1024)=r0; *(u32x4*)(ldst0+1*1024)=r1;
      *(u32x4*)(ldst0+2*1024)=r2; *(u32x4*)(ldst0+3*1024)=r3;
    }

    for (int t = 0; t < TSEQ; ++t){
      { // h1 peer poll (local fast w/ fallback), thr = t
        if (tid < 64){
          int useL = 0;
          const uint32_t thr = (uint32_t)t;
          const uint32_t* fl = flag1loc + (lane & 31)*FSTR;
          const uint32_t* fr = flag1rem + (lane & 31)*FSTR;
          if (fastSh){
            for (int it = 0; it < LPOLL; ++it)
              if (__all(ld_flag_sc0(fl) >= thr)){ useL = 1; break; }
          }
          if (!useL){
            for (;;){
              if (fastSh && __all(ld_flag_sc0(fl) >= thr)){ useL = 1; break; }
              if (__all(ld_ag(fr) >= thr)) break;
            }
            if (lane == 0 && !useL) fastSh = 0;
          }
          if (lane == 0) useLocSh = useL;
        }
        __syncthreads();
      }
      if (useLocSh){ // h1[t-1] from XCD-local ring
        const uint32_t* s1 = ring1loc + (size_t)((t+3) & 3)*8192;
        u32x4 q0,q1,q2,q3;
        LOAD4_SC0(s1+soff[0], s1+soff[1], s1+soff[2], s1+soff[3], q0,q1,q2,q3);
        VM_DRAIN;
        *(u32x4*)(ldst1+0*1024)=q0; *(u32x4*)(ldst1+1*1024)=q1;
        *(u32x4*)(ldst1+2*1024)=q2; *(u32x4*)(ldst1+3*1024)=q3;
      } else {
        const uint32_t* s1 = ring1rem + (size_t)((t+3) & 3)*8192;
        u32x4 q0,q1,q2,q3;
        LOAD4_AG(s1+soff[0], s1+soff[1], s1+soff[2], s1+soff[3], q0,q1,q2,q3);
        VM_DRAIN;
        *(u32x4*)(ldst1+0*1024)=q0; *(u32x4*)(ldst1+1*1024)=q1;
        *(u32x4*)(ldst1+2*1024)=q2; *(u32x4*)(ldst1+3*1024)=q3;
      }
      __syncthreads();

      f32x4 acc0 = {0.f,0.f,0.f,0.f}, acc1 = {0.f,0.f,0.f,0.f};
      #pragma unroll
      for (int c = 0; c < 8; ++c){
        const int cg = kh*8 + c;
        bf16x8 h1a0 = *(const bf16x8*)(&asmem1[((cg*2 + 0)*64 + lane)*16]);
        bf16x8 h1a1 = *(const bf16x8*)(&asmem1[((cg*2 + 1)*64 + lane)*16]);
        acc0 = __builtin_amdgcn_mfma_f32_16x16x32_bf16(h1a0, wfh[c], acc0, 0,0,0);
        acc1 = __builtin_amdgcn_mfma_f32_16x16x32_bf16(h1a1, wfh[c], acc1, 0,0,0);
        acc0 = __builtin_amdgcn_mfma_f32_16x16x32_bf16(h1a0, wfl[c], acc0, 0,0,0);
        acc1 = __builtin_amdgcn_mfma_f32_16x16x32_bf16(h1a1, wfl[c], acc1, 0,0,0);
        bf16x8 h0a0 = *(const bf16x8*)(&asmem0[((cg*2 + 0)*64 + lane)*16]);
        bf16x8 h0a1 = *(const bf16x8*)(&asmem0[((cg*2 + 1)*64 + lane)*16]);
        acc0 = __builtin_amdgcn_mfma_f32_16x16x32_bf16(h0a0, wxh[c], acc0, 0,0,0);
        acc1 = __builtin_amdgcn_mfma_f32_16x16x32_bf16(h0a1, wxh[c], acc1, 0,0,0);
        acc0 = __builtin_amdgcn_mfma_f32_16x16x32_bf16(h0a0, wxl[c], acc0, 0,0,0);
        acc1 = __builtin_amdgcn_mfma_f32_16x16x32_bf16(h0a1, wxl[c], acc1, 0,0,0);
      }
      {
        const int bq = (lane >> 4) * 4, ci = lane & 15;
        #pragma unroll
        for (int r = 0; r < 4; ++r){
          gsmem[wid][bq + r][ci]      = acc0[r];
          gsmem[wid][16 + bq + r][ci] = acc1[r];
        }
      }
      __syncthreads();
      {
        const float gv = ftanh_(gsmem[0][b][oi] + gsmem[1][b][oi] + bv[0]);
        const float iv = fsig (gsmem[2][b][oi] + gsmem[3][b][oi] + bv[1]);
        const float fv = fsig (gsmem[4][b][oi] + gsmem[5][b][oi] + bv[2]);
        const float ov = fsig (gsmem[6][b][oi] + gsmem[7][b][oi] + bv[3]);
        cst = fv*cst + iv*gv;
        const float hv = ov * ftanh_(cst);
        if (t == TSEQ-1) hfin[b*512 + og] = hv;
        const u16 hh = f2bf(hv);
        const int po = __shfl_xor((int)hh, 1, 64);
        if ((oi & 1) == 0){
          const uint32_t p = (uint32_t)hh | ((uint32_t)(po & 0xffff) << 16);
          st_wg(ring1loc + (size_t)(t & 3)*8192 + hoff, p);      // local leg FIRST
          CFENCE;
          st_ag(ring1rem + (size_t)(t & 3)*8192 + hoff, p);      // agent leg
        }
      }
      VM_WAIT1;
      __builtin_amdgcn_s_barrier();
      if (tid == 0) st_wg(flag1loc + j*FSTR, (uint32_t)(t+1));
      VM_DRAIN;
      __builtin_amdgcn_s_barrier();
      if (tid == 0) st_ag(flag1rem + j*FSTR, (uint32_t)(t+1));

      // tail: prefetch h0[t+1] (slot t+2, agent) - L0 runs ahead, instant
      if (t < TSEQ-1){
        if (tid < 64){
          const uint32_t* fr = flag0rem + (lane & 31)*FSTR;
          const uint32_t thr = (uint32_t)(t + 2);
          while (!__all(ld_ag(fr) >= thr)) {}
        }
        __syncthreads();
        const uint32_t* s0 = h0his + (size_t)(t+2)*8192;
        u32x4 r0,r1,r2,r3;
        LOAD4_AG(s0+soff[0], s0+soff[1], s0+soff[2], s0+soff[3], r0,r1,r2,r3);
        VM_DRAIN;
        *(u32x4*)(ldst0+0*1024)=r0; *(u32x4*)(ldst0+1*1024)=r1;
        *(u32x4*)(ldst0+2*1024)=r2; *(u32x4*)(ldst0+3*1024)=r3;
      }
    }
  }
}

// ------------------------------------------------------------------- FC out
__global__ void fc_kernel(const float* __restrict__ hfin,
                          const float* __restrict__ fcW, const float* __restrict__ fcb,
                          float* __restrict__ out)
{
  __shared__ float hbufs[512];
  const int b = blockIdx.x, tid = threadIdx.x;
  for (int i = tid; i < 512; i += 256)
    hbufs[i] = hfin[b*512 + i];
  __syncthreads();
  float acc = fcb[tid];
  const float4* w4 = (const float4*)(fcW + tid*512);
  #pragma unroll 8
  for (int k = 0; k < 128; ++k){
    const float4 w = w4[k];
    acc += hbufs[4*k]*w.x + hbufs[4*k+1]*w.y + hbufs[4*k+2]*w.z + hbufs[4*k+3]*w.w;
  }
  out[b*256 + tid] = acc;
}

// ---------------------------------------------------------------- launcher
extern "C" void kernel_launch(void* const* d_in, const int* in_sizes, int n_in,
                              void* d_out, int out_size, void* d_ws, size_t ws_size,
                              hipStream_t stream)
{
  const float* x   = (const float*)d_in[0];
  const float* Wx0 = (const float*)d_in[1];
  const float* bx0 = (const float*)d_in[2];
  const float* Wh0 = (const float*)d_in[3];
  const float* bh0 = (const float*)d_in[4];
  const float* Wx1 = (const float*)d_in[5];
  const float* bx1 = (const float*)d_in[6];
  const float* Wh1 = (const float*)d_in[7];
  const float* bh1 = (const float*)d_in[8];
  const float* fcW = (const float*)d_in[9];
  const float* fcb = (const float*)d_in[10];

  char* ws = (char*)d_ws;
  size_t off = 0;
  auto take = [&](size_t sz){ void* p = ws + off; off += sz; return p; };
  _Float16* xp    = (_Float16*)take((size_t)32768*2048*2);   // 128 MiB
  uint32_t* h0his = (uint32_t*)take((size_t)1025*8192*4);    // 33.6 MB h0 history
  u16*   xh      = (u16*)take((size_t)8388608*2);
  u16*   xl      = (u16*)take((size_t)8388608*2);
  u16*   wx0h    = (u16*)take((size_t)524288*2);
  u16*   wx0l    = (u16*)take((size_t)524288*2);
  u16*   wh0h    = (u16*)take((size_t)1048576*2);
  u16*   wh0l    = (u16*)take((size_t)1048576*2);
  u16*   wx1h    = (u16*)take((size_t)1048576*2);
  u16*   wx1l    = (u16*)take((size_t)1048576*2);
  u16*   wh1h    = (u16*)take((size_t)1048576*2);
  u16*   wh1l    = (u16*)take((size_t)1048576*2);
  uint32_t* ring0loc = (uint32_t*)take((size_t)4*8192*4);    // 128 KB
  uint32_t* ring1loc = (uint32_t*)take((size_t)4*8192*4);    // 128 KB
  uint32_t* ring1rem = (uint32_t*)take((size_t)4*8192*4);    // 128 KB
  float* hfin    = (float*)take((size_t)32*512*4);
  float* bs0     = (float*)take(2048*4);
  float* bs1     = (float*)take(2048*4);
  uint32_t* flag0loc = (uint32_t*)take((size_t)32*FSTR*4);   // contiguous flag
  uint32_t* flag1loc = (uint32_t*)take((size_t)32*FSTR*4);   // + xcdbuf region
  uint32_t* flag0rem = (uint32_t*)take((size_t)32*FSTR*4);
  uint32_t* flag1rem = (uint32_t*)take((size_t)32*FSTR*4);
  uint32_t* xcdbuf   = (uint32_t*)take((size_t)64*FSTR*4);
  (void)in_sizes; (void)n_in; (void)out_size; (void)ws_size;

  // flags/xcdbuf hygiene each launch/replay (one contiguous memset, 12 KB)
  (void)hipMemsetAsync(flag0loc, 0, (size_t)(32*4 + 64)*FSTR*4, stream);

  split_f32<<<4096,256,0,stream>>>(x,   xh,   xl,   8388608);
  split_f32<<<1024,256,0,stream>>>(Wx0, wx0h, wx0l, 524288);
  split_f32<<<2048,256,0,stream>>>(Wh0, wh0h, wh0l, 1048576);
  split_f32<<<2048,256,0,stream>>>(Wx1, wx1h, wx1l, 1048576);
  split_f32<<<2048,256,0,stream>>>(Wh1, wh1h, wh1l, 1048576);
  vec_add<<<8,256,0,stream>>>(bx0, bh0, bs0, 2048);
  vec_add<<<8,256,0,stream>>>(bx1, bh1, bs1, 2048);
  init_state<<<32,256,0,stream>>>(h0his, ring0loc, ring1loc, ring1rem);

  dim3 gg(16, 256);
  gemm_split<<<gg,256,0,stream>>>(xh, xl, wx0h, wx0l, bs0, xp, 256);
  lstm_fused<<<256,512,0,stream>>>(xp, wh0h, wh0l, wh1h, wh1l, wx1h, wx1l, bs1,
                                   h0his, ring0loc, ring1loc, ring1rem,
                                   flag0loc, flag1loc, flag0rem, flag1rem,
                                   xcdbuf, hfin);
  fc_kernel<<<32,256,0,stream>>>(hfin, fcW, fcb, (float*)d_out);
}